// Round 2
// baseline (48.105 us; speedup 1.0000x reference)
//
#include <hip/hip_runtime.h>

// DiversityLoss: attention_maps [B=64, M=32, H*W=16384] fp32.
// gram[b,i,j] = sum_k (A[b,i,k]^2 * A[b,j,k]^2); loss = mean_b sum_{i<j} relu(0.1-gram)/496.
//
// HBM floor: 134 MB / 6.5 TB/s ~= 21 us. Round-1 (4x4 tiles) was LDS-issue-bound
// (2 ds_read_b128 per 16 FMA -> 41 us model, 44.7 measured). This round: 8x8 tiles
// with 4-way k-group split per wave -> 1 ds_read_b128 per 16 FMA, plus b128 staging
// writes via transposed float2 global loads (was: 4-way-conflicted scalar b32).

#define MARGIN 0.1f

constexpr int B_ = 64;
constexpr int M_ = 32;
constexpr int K_ = 16384;
constexpr int NC = 8;            // chunks per batch -> grid 512 = exactly 2 blocks/CU
constexpr int KC = K_ / NC;      // 2048
constexpr int TS = 256;          // k per LDS subtile
constexpr int NSUB = KC / TS;    // 8
constexpr int LST = 36;          // dwords per k-row (32 + 4 pad)

__global__ __launch_bounds__(256, 2) void gram_partial(const float* __restrict__ A,
                                                       float* __restrict__ ws_g) {
  __shared__ float lds[TS * LST];  // 36 KiB

  const int tid  = threadIdx.x;
  const int w    = tid >> 6;       // wave 0..3
  const int lane = tid & 63;

  const int b = blockIdx.x >> 3;   // batch
  const int c = blockIdx.x & (NC - 1);

  // --- staging coords: thread loads 4 rows x (2k x 4 u-slices), transposed ---
  const int h  = lane >> 5;        // 0/1
  const int kl = lane & 31;        // k-pair lane 0..31
  const int r0 = (w * 2 + h) * 4;  // row-quad base: 0,4,...,28

  // --- compute coords: 16 lanes cover 32x32 gram as 4x4 grid of 8x8 tiles; 4 k-groups ---
  const int g   = lane >> 4;       // k-group 0..3
  const int lid = lane & 15;
  const int tr  = lid >> 2;        // tile row 0..3 (rows tr*8..+7)
  const int tc  = lid & 3;         // tile col 0..3

  const float2* A2 = reinterpret_cast<const float2*>(A);
  const size_t rowstride2 = K_ / 2;  // 8192
  const size_t base2 = (size_t)(b * M_ + r0) * rowstride2 + (size_t)c * (KC / 2) + kl;

  float2 v[4][4];  // [u][row-in-quad]

  // prologue: load + stage subtile 0
#pragma unroll
  for (int u = 0; u < 4; ++u)
#pragma unroll
    for (int i = 0; i < 4; ++i)
      v[u][i] = A2[base2 + (size_t)i * rowstride2 + u * 32];

#pragma unroll
  for (int u = 0; u < 4; ++u) {
    const int k0 = u * 64 + kl * 2;
    float4 q0, q1;
    q0.x = v[u][0].x * v[u][0].x; q0.y = v[u][1].x * v[u][1].x;
    q0.z = v[u][2].x * v[u][2].x; q0.w = v[u][3].x * v[u][3].x;
    q1.x = v[u][0].y * v[u][0].y; q1.y = v[u][1].y * v[u][1].y;
    q1.z = v[u][2].y * v[u][2].y; q1.w = v[u][3].y * v[u][3].y;
    *reinterpret_cast<float4*>(&lds[(k0 + 0) * LST + r0]) = q0;
    *reinterpret_cast<float4*>(&lds[(k0 + 1) * LST + r0]) = q1;
  }
  __syncthreads();

  float acc[8][8];
#pragma unroll
  for (int p = 0; p < 8; ++p)
#pragma unroll
    for (int q = 0; q < 8; ++q) acc[p][q] = 0.0f;

  const float4* L4 = reinterpret_cast<const float4*>(lds);

  for (int s = 0; s < NSUB; ++s) {
    // prefetch next subtile into registers (flies under the compute below)
    if (s + 1 < NSUB) {
#pragma unroll
      for (int u = 0; u < 4; ++u)
#pragma unroll
        for (int i = 0; i < 4; ++i)
          v[u][i] = A2[base2 + (size_t)i * rowstride2 + (s + 1) * (TS / 2) + u * 32];
    }

    // compute: wave w owns k in [w*64, w*64+64); group g takes k = base+it*4+g
#pragma unroll 4
    for (int it = 0; it < 16; ++it) {
      const int k = w * 64 + it * 4 + g;
      const float4* Lk = L4 + k * (LST / 4);
      const float4 a0 = Lk[tr * 2];
      const float4 a1 = Lk[tr * 2 + 1];
      const float4 b0 = Lk[tc * 2];
      const float4 b1 = Lk[tc * 2 + 1];
      const float av[8] = {a0.x, a0.y, a0.z, a0.w, a1.x, a1.y, a1.z, a1.w};
      const float bv[8] = {b0.x, b0.y, b0.z, b0.w, b1.x, b1.y, b1.z, b1.w};
#pragma unroll
      for (int p = 0; p < 8; ++p)
#pragma unroll
        for (int q = 0; q < 8; ++q) acc[p][q] = fmaf(av[p], bv[q], acc[p][q]);
    }

    if (s + 1 < NSUB) {
      __syncthreads();  // everyone done reading this subtile
#pragma unroll
      for (int u = 0; u < 4; ++u) {
        const int k0 = u * 64 + kl * 2;
        float4 q0, q1;
        q0.x = v[u][0].x * v[u][0].x; q0.y = v[u][1].x * v[u][1].x;
        q0.z = v[u][2].x * v[u][2].x; q0.w = v[u][3].x * v[u][3].x;
        q1.x = v[u][0].y * v[u][0].y; q1.y = v[u][1].y * v[u][1].y;
        q1.z = v[u][2].y * v[u][2].y; q1.w = v[u][3].y * v[u][3].y;
        *reinterpret_cast<float4*>(&lds[(k0 + 0) * LST + r0]) = q0;
        *reinterpret_cast<float4*>(&lds[(k0 + 1) * LST + r0]) = q1;
      }
      __syncthreads();  // staged data visible
    }
  }

  // reduce k-group partials across lanes (xor 16, then 32)
#pragma unroll
  for (int p = 0; p < 8; ++p)
#pragma unroll
    for (int q = 0; q < 8; ++q) {
      float t = acc[p][q];
      t += __shfl_xor(t, 16);
      t += __shfl_xor(t, 32);
      acc[p][q] = t;
    }

  __syncthreads();  // staging buffer now dead; reuse for cross-wave reduction

  if (g == 0) {
#pragma unroll
    for (int p = 0; p < 8; ++p) {
      const int off = w * 1024 + (tr * 8 + p) * 32 + tc * 8;
      float4 lo, hi;
      lo.x = acc[p][0]; lo.y = acc[p][1]; lo.z = acc[p][2]; lo.w = acc[p][3];
      hi.x = acc[p][4]; hi.y = acc[p][5]; hi.z = acc[p][6]; hi.w = acc[p][7];
      *reinterpret_cast<float4*>(&lds[off]) = lo;
      *reinterpret_cast<float4*>(&lds[off + 4]) = hi;
    }
  }
  __syncthreads();

  const float4 s0 = L4[tid];
  const float4 s1 = L4[256 + tid];
  const float4 s2 = L4[512 + tid];
  const float4 s3 = L4[768 + tid];
  float4 o;
  o.x = s0.x + s1.x + s2.x + s3.x;
  o.y = s0.y + s1.y + s2.y + s3.y;
  o.z = s0.z + s1.z + s2.z + s3.z;
  o.w = s0.w + s1.w + s2.w + s3.w;
  reinterpret_cast<float4*>(ws_g)[(size_t)blockIdx.x * 256 + tid] = o;
}

// Kernel 2: per-batch -> sum chunk partials, relu margin, strict upper triangle.
__global__ __launch_bounds__(256) void reduce_batch(const float* __restrict__ ws_g,
                                                    float* __restrict__ ws_b) {
  const int b   = blockIdx.x;
  const int tid = threadIdx.x;
  const float4* G4 = reinterpret_cast<const float4*>(ws_g);

  float4 s = make_float4(0.f, 0.f, 0.f, 0.f);
#pragma unroll
  for (int c = 0; c < NC; ++c) {
    const float4 t = G4[((size_t)(b * NC + c)) * 256 + tid];
    s.x += t.x; s.y += t.y; s.z += t.z; s.w += t.w;
  }
  const float gv[4] = {s.x, s.y, s.z, s.w};
  float local = 0.f;
#pragma unroll
  for (int e = 0; e < 4; ++e) {
    const int idx = tid * 4 + e;
    const int ii = idx >> 5;
    const int jj = idx & 31;
    if (jj > ii) local += fmaxf(MARGIN - gv[e], 0.0f);
  }

  float vv = local;
#pragma unroll
  for (int off = 32; off > 0; off >>= 1) vv += __shfl_down(vv, off);
  __shared__ float red[4];
  if ((tid & 63) == 0) red[tid >> 6] = vv;
  __syncthreads();
  if (tid == 0) ws_b[b] = (red[0] + red[1] + red[2] + red[3]) * (1.0f / 496.0f);
}

// Kernel 3: mean over batches.
__global__ void final_mean(const float* __restrict__ ws_b, float* __restrict__ out) {
  float v = ws_b[threadIdx.x];  // 64 threads
#pragma unroll
  for (int off = 32; off > 0; off >>= 1) v += __shfl_down(v, off);
  if (threadIdx.x == 0) out[0] = v * (1.0f / 64.0f);
}

extern "C" void kernel_launch(void* const* d_in, const int* in_sizes, int n_in,
                              void* d_out, int out_size, void* d_ws, size_t ws_size,
                              hipStream_t stream) {
  const float* A = reinterpret_cast<const float*>(d_in[0]);
  float* out = reinterpret_cast<float*>(d_out);

  // ws: [512 blocks][1024 floats] partial grams (2 MiB) + [64] per-batch losses
  float* ws_g = reinterpret_cast<float*>(d_ws);
  float* ws_b = ws_g + (size_t)B_ * NC * M_ * M_;

  gram_partial<<<B_ * NC, 256, 0, stream>>>(A, ws_g);
  reduce_batch<<<B_, 256, 0, stream>>>(ws_g, ws_b);
  final_mean<<<1, 64, 0, stream>>>(ws_b, out);
}